// Round 3
// baseline (400.451 us; speedup 1.0000x reference)
//
#include <hip/hip_runtime.h>
#include <math.h>

#define NB 32
#define NV 2048
#define NC 64
#define NT 64
#define VC 32           // v-values per block in kernel 1

// ---------------------------------------------------------------------------
// Kernel 1: one pass over x (1 GiB), wave-autonomous (NO barriers in v-loop).
// Wave w of each block owns u-slice [w*16, w*16+16); lane l owns
//   u = w*16 + (l&3)*4 .. +3   and rows c = (l>>2) + 16k, k=0..3.
// Per v: lane loads 4 float4 of x, accumulates
//   t1r[k][j] += U1[v] * x[v, c_k, u_j]
//   rh[j]      = sum_k U3[c_k] * x[v, c_k, u_j]   (in-lane partial over 4 rows)
// then a 4-step shfl_xor butterfly (strides 4,8,16,32) completes
// rhs[v,u_j] = sum over all 64 c within the wave, and
//   mr[k][j] += U2[c_k, v] * rhs[v, u_j].
// Epilogue: atomicAdd fragments into tmp1g / Mg (pre-zeroed).
// ---------------------------------------------------------------------------
__global__ __launch_bounds__(256) void k1_pass_x(
    const float* __restrict__ x,
    const float* __restrict__ U1,
    const float* __restrict__ U2,   // (C, V)
    const float* __restrict__ U3,   // (C)
    float* __restrict__ tmp1g,      // (B, C, T), pre-zeroed
    float* __restrict__ Mg)         // (B, C, T), pre-zeroed
{
    const int tid = threadIdx.x;
    const int blk = blockIdx.x;
    const int b  = blk / (NV / VC);
    const int v0 = (blk % (NV / VC)) * VC;

    const int w     = tid >> 6;      // wave 0..3
    const int l     = tid & 63;      // lane
    const int u0    = w * 16 + (l & 3) * 4;  // float4-aligned t/u offset
    const int cbase = l >> 2;        // c = cbase + 16k

    __shared__ float U2s[VC][NC];    // [vi][c], 8 KB

    // stage U2 chunk (coalesced in v, 32-wide rows)
    for (int i = tid; i < VC * NC; i += 256) {
        const int c  = i >> 5;       // 0..63
        const int vi = i & 31;       // 0..31
        U2s[vi][c] = U2[c * NV + v0 + vi];
    }

    float u3r[4];
#pragma unroll
    for (int k = 0; k < 4; ++k) u3r[k] = U3[cbase + 16 * k];

    float4 t1r[4], mr[4];
#pragma unroll
    for (int k = 0; k < 4; ++k) {
        t1r[k] = make_float4(0.f, 0.f, 0.f, 0.f);
        mr[k]  = make_float4(0.f, 0.f, 0.f, 0.f);
    }

    __syncthreads();   // U2s ready; last barrier before epilogue

    const float* xb = x + (size_t)(b * NV + v0) * NC * NT + u0;

#pragma unroll 4
    for (int vi = 0; vi < VC; ++vi) {
        const float* xv = xb + (size_t)vi * NC * NT;

        float4 xa[4];
#pragma unroll
        for (int k = 0; k < 4; ++k)
            xa[k] = *reinterpret_cast<const float4*>(xv + (cbase + 16 * k) * NT);

        const float u1v = U1[v0 + vi];

        float4 rh = make_float4(0.f, 0.f, 0.f, 0.f);
#pragma unroll
        for (int k = 0; k < 4; ++k) {
            t1r[k].x = fmaf(u1v, xa[k].x, t1r[k].x);
            t1r[k].y = fmaf(u1v, xa[k].y, t1r[k].y);
            t1r[k].z = fmaf(u1v, xa[k].z, t1r[k].z);
            t1r[k].w = fmaf(u1v, xa[k].w, t1r[k].w);
            rh.x = fmaf(u3r[k], xa[k].x, rh.x);
            rh.y = fmaf(u3r[k], xa[k].y, rh.y);
            rh.z = fmaf(u3r[k], xa[k].z, rh.z);
            rh.w = fmaf(u3r[k], xa[k].w, rh.w);
        }

        // intra-wave butterfly: sum over the 16 lane-groups (stride 4,8,16,32)
#pragma unroll
        for (int m = 4; m <= 32; m <<= 1) {
            rh.x += __shfl_xor(rh.x, m, 64);
            rh.y += __shfl_xor(rh.y, m, 64);
            rh.z += __shfl_xor(rh.z, m, 64);
            rh.w += __shfl_xor(rh.w, m, 64);
        }

#pragma unroll
        for (int k = 0; k < 4; ++k) {
            const float u2v = U2s[vi][cbase + 16 * k];
            mr[k].x = fmaf(u2v, rh.x, mr[k].x);
            mr[k].y = fmaf(u2v, rh.y, mr[k].y);
            mr[k].z = fmaf(u2v, rh.z, mr[k].z);
            mr[k].w = fmaf(u2v, rh.w, mr[k].w);
        }
    }

    float* t1b = tmp1g + (size_t)b * NC * NT;
    float* mb  = Mg    + (size_t)b * NC * NT;
#pragma unroll
    for (int k = 0; k < 4; ++k) {
        const int off = (cbase + 16 * k) * NT + u0;
        atomicAdd(&t1b[off + 0], t1r[k].x);
        atomicAdd(&t1b[off + 1], t1r[k].y);
        atomicAdd(&t1b[off + 2], t1r[k].z);
        atomicAdd(&t1b[off + 3], t1r[k].w);
        atomicAdd(&mb[off + 0], mr[k].x);
        atomicAdd(&mb[off + 1], mr[k].y);
        atomicAdd(&mb[off + 2], mr[k].z);
        atomicAdd(&mb[off + 3], mr[k].w);
    }
}

// ---------------------------------------------------------------------------
// Kernel 2: per-b epilogue (tiny). product = tmp1^T(c,t) · M(c,u); sigmoid(+b_e);
// E = V_e @ sig; softmax over t (axis=1) per column u.
// ---------------------------------------------------------------------------
__global__ __launch_bounds__(256) void k2_epilogue(
    const float* __restrict__ tmp1g,  // (B, C, T)
    const float* __restrict__ Mg,     // (B, C, T)
    const float* __restrict__ b_e,    // (1, T, T)
    const float* __restrict__ V_e,    // (B, T, T)
    float* __restrict__ out)          // (B, T, T)
{
    const int b = blockIdx.x;
    const int tid = threadIdx.x;

    __shared__ float t1[NC * NT];
    __shared__ float Mb[NC * NT];
    __shared__ float P[NT * NT];
    __shared__ float Eb[NT * NT];

    const float* t1g = tmp1g + (size_t)b * NC * NT;
    const float* mgb = Mg    + (size_t)b * NC * NT;
    for (int i = tid * 4; i < NC * NT; i += 1024) {
        *reinterpret_cast<float4*>(&t1[i]) = *reinterpret_cast<const float4*>(&t1g[i]);
        *reinterpret_cast<float4*>(&Mb[i]) = *reinterpret_cast<const float4*>(&mgb[i]);
    }
    __syncthreads();

    const int u  = tid & 63;
    const int tg = tid >> 6;   // wave id, 0..3

    // product + sigmoid
    for (int i = 0; i < 16; ++i) {
        const int t = tg * 16 + i;
        float acc = 0.f;
#pragma unroll 8
        for (int c = 0; c < NC; ++c)
            acc = fmaf(t1[c * NT + t], Mb[c * NT + u], acc);
        const float z = acc + b_e[t * NT + u];
        P[t * NT + u] = 1.0f / (1.0f + expf(-z));
    }
    __syncthreads();

    // E = V_e @ P
    const float* veb = V_e + (size_t)b * NT * NT;
    for (int i = 0; i < 16; ++i) {
        const int t = tg * 16 + i;
        float acc = 0.f;
#pragma unroll 8
        for (int s = 0; s < NT; ++s)
            acc = fmaf(veb[t * NT + s], P[s * NT + u], acc);
        Eb[t * NT + u] = acc;
    }
    __syncthreads();

    // softmax over t for each column u
    if (tid < NT) {
        const int uu = tid;
        float m = -INFINITY;
        for (int t = 0; t < NT; ++t) m = fmaxf(m, Eb[t * NT + uu]);
        float ssum = 0.f;
        for (int t = 0; t < NT; ++t) {
            const float e = expf(Eb[t * NT + uu] - m);
            Eb[t * NT + uu] = e;
            ssum += e;
        }
        const float inv = 1.0f / ssum;
        for (int t = 0; t < NT; ++t)
            out[(size_t)b * NT * NT + t * NT + uu] = Eb[t * NT + uu] * inv;
    }
}

extern "C" void kernel_launch(void* const* d_in, const int* in_sizes, int n_in,
                              void* d_out, int out_size, void* d_ws, size_t ws_size,
                              hipStream_t stream) {
    const float* x   = (const float*)d_in[0];
    const float* U1  = (const float*)d_in[1];
    const float* U2  = (const float*)d_in[2];
    const float* U3  = (const float*)d_in[3];
    const float* b_e = (const float*)d_in[4];
    const float* V_e = (const float*)d_in[5];
    float* out = (float*)d_out;

    float* tmp1 = (float*)d_ws;
    float* Mg   = tmp1 + (size_t)NB * NC * NT;

    // accumulated via atomics -> must re-zero every call
    hipMemsetAsync(d_ws, 0, (size_t)2 * NB * NC * NT * sizeof(float), stream);

    k1_pass_x<<<NB * (NV / VC), 256, 0, stream>>>(x, U1, U2, U3, tmp1, Mg);
    k2_epilogue<<<NB, 256, 0, stream>>>(tmp1, Mg, b_e, V_e, out);
}

// Round 4
// 306.249 us; speedup vs baseline: 1.3076x; 1.3076x over previous
//
#include <hip/hip_runtime.h>
#include <math.h>

#define NB 32
#define NV 2048
#define NC 64
#define NT 64
#define VC 32              // v-values per block in kernel 1
#define CHUNKS (NV / VC)   // 64 chunks per b

// ---------------------------------------------------------------------------
// Kernel 1: one pass over x (1 GiB), wave-autonomous (no barriers in v-loop).
// Wave w of each block owns u-slice [w*16, w*16+16); lane l owns
//   u = w*16 + (l&3)*4 .. +3   and rows c = (l>>2) + 16k, k=0..3.
// Accumulates in registers across VC v-values:
//   t1r[k] += U1[v] * x[v, c_k, u0..u0+3]
//   rhs[v,u] = sum_c U3[c] x[v,c,u]  (in-lane partial + 4-step shfl butterfly)
//   mr[k]  += U2[c_k, v] * rhs[v, u0..u0+3]
// Epilogue: plain float4 stores into a per-(b,chunk) private workspace slot.
// NO atomics, NO pre-zeroing required.
// ---------------------------------------------------------------------------
__global__ __launch_bounds__(256) void k1_pass_x(
    const float* __restrict__ x,
    const float* __restrict__ U1,
    const float* __restrict__ U2,   // (C, V)
    const float* __restrict__ U3,   // (C)
    float* __restrict__ part)       // (B, CHUNKS, 2, C, T)
{
    const int tid = threadIdx.x;
    const int blk = blockIdx.x;
    const int b     = blk / CHUNKS;
    const int chunk = blk % CHUNKS;
    const int v0    = chunk * VC;

    const int w     = tid >> 6;      // wave 0..3
    const int l     = tid & 63;      // lane
    const int u0    = w * 16 + (l & 3) * 4;  // float4-aligned t/u offset
    const int cbase = l >> 2;        // c = cbase + 16k

    __shared__ float U2s[VC][NC];    // [vi][c], 8 KB

    for (int i = tid; i < VC * NC; i += 256) {
        const int c  = i >> 5;
        const int vi = i & 31;
        U2s[vi][c] = U2[c * NV + v0 + vi];
    }

    float u3r[4];
#pragma unroll
    for (int k = 0; k < 4; ++k) u3r[k] = U3[cbase + 16 * k];

    float4 t1r[4], mr[4];
#pragma unroll
    for (int k = 0; k < 4; ++k) {
        t1r[k] = make_float4(0.f, 0.f, 0.f, 0.f);
        mr[k]  = make_float4(0.f, 0.f, 0.f, 0.f);
    }

    __syncthreads();   // U2s ready; only barrier in the kernel

    const float* xb = x + (size_t)(b * NV + v0) * NC * NT + u0;

#pragma unroll 4
    for (int vi = 0; vi < VC; ++vi) {
        const float* xv = xb + (size_t)vi * NC * NT;

        float4 xa[4];
#pragma unroll
        for (int k = 0; k < 4; ++k)
            xa[k] = *reinterpret_cast<const float4*>(xv + (cbase + 16 * k) * NT);

        const float u1v = U1[v0 + vi];

        float4 rh = make_float4(0.f, 0.f, 0.f, 0.f);
#pragma unroll
        for (int k = 0; k < 4; ++k) {
            t1r[k].x = fmaf(u1v, xa[k].x, t1r[k].x);
            t1r[k].y = fmaf(u1v, xa[k].y, t1r[k].y);
            t1r[k].z = fmaf(u1v, xa[k].z, t1r[k].z);
            t1r[k].w = fmaf(u1v, xa[k].w, t1r[k].w);
            rh.x = fmaf(u3r[k], xa[k].x, rh.x);
            rh.y = fmaf(u3r[k], xa[k].y, rh.y);
            rh.z = fmaf(u3r[k], xa[k].z, rh.z);
            rh.w = fmaf(u3r[k], xa[k].w, rh.w);
        }

        // intra-wave butterfly over 16 c-groups (strides 4,8,16,32)
#pragma unroll
        for (int m = 4; m <= 32; m <<= 1) {
            rh.x += __shfl_xor(rh.x, m, 64);
            rh.y += __shfl_xor(rh.y, m, 64);
            rh.z += __shfl_xor(rh.z, m, 64);
            rh.w += __shfl_xor(rh.w, m, 64);
        }

#pragma unroll
        for (int k = 0; k < 4; ++k) {
            const float u2v = U2s[vi][cbase + 16 * k];
            mr[k].x = fmaf(u2v, rh.x, mr[k].x);
            mr[k].y = fmaf(u2v, rh.y, mr[k].y);
            mr[k].z = fmaf(u2v, rh.z, mr[k].z);
            mr[k].w = fmaf(u2v, rh.w, mr[k].w);
        }
    }

    // plain stores into this block's private slot: part[b][chunk][a][c][t]
    float* pb = part + (size_t)(b * CHUNKS + chunk) * 2 * NC * NT;
#pragma unroll
    for (int k = 0; k < 4; ++k) {
        const int off = (cbase + 16 * k) * NT + u0;
        *reinterpret_cast<float4*>(&pb[off])           = t1r[k];
        *reinterpret_cast<float4*>(&pb[NC * NT + off]) = mr[k];
    }
}

// ---------------------------------------------------------------------------
// Kernel 2a: reduce the 64 chunk-partials per b.
// part: (B, CHUNKS, 2*C*T) -> fin: (B, 2*C*T). 256 blocks x 256 threads,
// 1 float4 output per thread, 64-iteration chunk loop (contiguous 4 KB reads).
// ---------------------------------------------------------------------------
__global__ __launch_bounds__(256) void k2a_reduce(
    const float4* __restrict__ part4,   // (B, CHUNKS, 2048) in float4 units
    float4* __restrict__ fin4)          // (B, 2048)
{
    const int j = blockIdx.x;           // 0..255
    const int b = j >> 3;
    const int local = (j & 7) * 256 + threadIdx.x;  // 0..2047

    const float4* p = part4 + (size_t)b * CHUNKS * 2048 + local;
    float4 acc = make_float4(0.f, 0.f, 0.f, 0.f);
#pragma unroll 8
    for (int ch = 0; ch < CHUNKS; ++ch) {
        const float4 v = p[(size_t)ch * 2048];
        acc.x += v.x; acc.y += v.y; acc.z += v.z; acc.w += v.w;
    }
    fin4[(size_t)b * 2048 + local] = acc;
}

// ---------------------------------------------------------------------------
// Kernel 2b: per-b epilogue. product = t1^T(c,t) · M(c,u); sigmoid(+b_e);
// E = V_e @ sig; softmax over t (axis=1) per column u.
// ---------------------------------------------------------------------------
__global__ __launch_bounds__(256) void k2b_epilogue(
    const float* __restrict__ fin,    // (B, 2, C, T)
    const float* __restrict__ b_e,    // (1, T, T)
    const float* __restrict__ V_e,    // (B, T, T)
    float* __restrict__ out)          // (B, T, T)
{
    const int b = blockIdx.x;
    const int tid = threadIdx.x;

    __shared__ float t1[NC * NT];
    __shared__ float Mb[NC * NT];
    __shared__ float P[NT * NT];
    __shared__ float Eb[NT * NT];

    const float* t1g = fin + (size_t)b * 2 * NC * NT;
    const float* mgb = t1g + NC * NT;
    for (int i = tid * 4; i < NC * NT; i += 1024) {
        *reinterpret_cast<float4*>(&t1[i]) = *reinterpret_cast<const float4*>(&t1g[i]);
        *reinterpret_cast<float4*>(&Mb[i]) = *reinterpret_cast<const float4*>(&mgb[i]);
    }
    __syncthreads();

    const int u  = tid & 63;
    const int tg = tid >> 6;   // wave id, 0..3

    for (int i = 0; i < 16; ++i) {
        const int t = tg * 16 + i;
        float acc = 0.f;
#pragma unroll 8
        for (int c = 0; c < NC; ++c)
            acc = fmaf(t1[c * NT + t], Mb[c * NT + u], acc);
        const float z = acc + b_e[t * NT + u];
        P[t * NT + u] = 1.0f / (1.0f + expf(-z));
    }
    __syncthreads();

    const float* veb = V_e + (size_t)b * NT * NT;
    for (int i = 0; i < 16; ++i) {
        const int t = tg * 16 + i;
        float acc = 0.f;
#pragma unroll 8
        for (int s = 0; s < NT; ++s)
            acc = fmaf(veb[t * NT + s], P[s * NT + u], acc);
        Eb[t * NT + u] = acc;
    }
    __syncthreads();

    if (tid < NT) {
        const int uu = tid;
        float m = -INFINITY;
        for (int t = 0; t < NT; ++t) m = fmaxf(m, Eb[t * NT + uu]);
        float ssum = 0.f;
        for (int t = 0; t < NT; ++t) {
            const float e = expf(Eb[t * NT + uu] - m);
            Eb[t * NT + uu] = e;
            ssum += e;
        }
        const float inv = 1.0f / ssum;
        for (int t = 0; t < NT; ++t)
            out[(size_t)b * NT * NT + t * NT + uu] = Eb[t * NT + uu] * inv;
    }
}

extern "C" void kernel_launch(void* const* d_in, const int* in_sizes, int n_in,
                              void* d_out, int out_size, void* d_ws, size_t ws_size,
                              hipStream_t stream) {
    const float* x   = (const float*)d_in[0];
    const float* U1  = (const float*)d_in[1];
    const float* U2  = (const float*)d_in[2];
    const float* U3  = (const float*)d_in[3];
    const float* b_e = (const float*)d_in[4];
    const float* V_e = (const float*)d_in[5];
    float* out = (float*)d_out;

    float* part = (float*)d_ws;                                   // 64 MB
    float* fin  = part + (size_t)NB * CHUNKS * 2 * NC * NT;       // 1 MB

    // every byte of part/fin is fully written each call -> no zeroing needed
    k1_pass_x<<<NB * CHUNKS, 256, 0, stream>>>(x, U1, U2, U3, part);
    k2a_reduce<<<256, 256, 0, stream>>>((const float4*)part, (float4*)fin);
    k2b_epilogue<<<NB, 256, 0, stream>>>(fin, b_e, V_e, out);
}

// Round 5
// 257.228 us; speedup vs baseline: 1.5568x; 1.1906x over previous
//
#include <hip/hip_runtime.h>
#include <math.h>

#define NB 32
#define NV 2048
#define NC 64
#define NT 64
#define VC 64              // v-values per block in kernel 1
#define CHUNKS (NV / VC)   // 32 chunks per b
#define U2P 68             // padded LDS stride (16B-aligned, bank-spread)

// ---------------------------------------------------------------------------
// Kernel 1: one pass over x (1 GiB). Perfectly-coalesced loads, no per-v
// barriers. Wave w owns c-quarter [16w,16w+16), all 64 u. Lane l:
//   u0 = (l&15)*4, crow = l>>4, rows c_k = 16w + 4k + crow (k=0..3).
// Per load instruction k the wave reads 4 consecutive rows x 256B = one
// contiguous 1KB segment.
// Per v:
//   t1r[k] += U1[v] * xa[k]                       (c_k rows of tmp1)
//   rh = sum_k U3[c_k]*xa[k]; 2-step shfl_xor(16,32) -> rhs_w[v,u0..3]
//        (partial over this wave's 16 c)
//   mr[j] += U2[crow*16+j, v] * rh   (j=0..15: each wave covers ALL 64 c,
//        using only its own rhs_w -- valid by linearity of M in rhs)
// Block end: t1 stored directly; M = sum of 4 wave-partials via LDS (4
// barriers, once per block); both written as plain float4 stores to a
// private workspace slot. No atomics, no pre-zeroing.
// ---------------------------------------------------------------------------
__global__ __launch_bounds__(256) void k1_pass_x(
    const float* __restrict__ x,
    const float* __restrict__ U1,
    const float* __restrict__ U2,   // (C, V)
    const float* __restrict__ U3,   // (C)
    float* __restrict__ part)       // (B, CHUNKS, 2, C, T)
{
    const int tid = threadIdx.x;
    const int blk = blockIdx.x;
    const int b     = blk / CHUNKS;
    const int chunk = blk % CHUNKS;
    const int v0    = chunk * VC;

    const int w    = tid >> 6;        // wave 0..3
    const int l    = tid & 63;        // lane
    const int u0   = (l & 15) * 4;    // float4-aligned u offset (full row span)
    const int crow = l >> 4;          // 0..3
    const int cw   = w * 16 + crow;   // lane base row; c_k = cw + 4k

    __shared__ float U2s[VC][U2P];    // [vi][c], padded
    __shared__ float Msum[NC * NT];   // 16 KB wave-partial reduce buffer

    // stage U2 chunk: global reads coalesced along v; padded LDS writes
    for (int i = tid; i < VC * NC; i += 256) {
        const int c  = i >> 6;        // 0..63
        const int vi = i & 63;        // 0..63
        U2s[vi][c] = U2[c * NV + v0 + vi];
    }

    float u3r[4];
#pragma unroll
    for (int k = 0; k < 4; ++k) u3r[k] = U3[cw + 4 * k];

    float4 t1r[4], mr[16];
#pragma unroll
    for (int k = 0; k < 4; ++k) t1r[k] = make_float4(0.f, 0.f, 0.f, 0.f);
#pragma unroll
    for (int j = 0; j < 16; ++j) mr[j] = make_float4(0.f, 0.f, 0.f, 0.f);

    __syncthreads();   // U2s ready

    const float* xb = x + (size_t)(b * NV + v0) * (NC * NT) + cw * NT + u0;

    for (int vi = 0; vi < VC; ++vi) {
        const float* xv = xb + (size_t)vi * (NC * NT);

        float4 xa[4];
#pragma unroll
        for (int k = 0; k < 4; ++k)
            xa[k] = *reinterpret_cast<const float4*>(xv + 4 * k * NT);

        const float u1v = U1[v0 + vi];

        float4 rh = make_float4(0.f, 0.f, 0.f, 0.f);
#pragma unroll
        for (int k = 0; k < 4; ++k) {
            t1r[k].x = fmaf(u1v, xa[k].x, t1r[k].x);
            t1r[k].y = fmaf(u1v, xa[k].y, t1r[k].y);
            t1r[k].z = fmaf(u1v, xa[k].z, t1r[k].z);
            t1r[k].w = fmaf(u1v, xa[k].w, t1r[k].w);
            rh.x = fmaf(u3r[k], xa[k].x, rh.x);
            rh.y = fmaf(u3r[k], xa[k].y, rh.y);
            rh.z = fmaf(u3r[k], xa[k].z, rh.z);
            rh.w = fmaf(u3r[k], xa[k].w, rh.w);
        }

        // complete rhs over this wave's 16 c: sum the 4 crow groups
#pragma unroll
        for (int m = 16; m <= 32; m <<= 1) {
            rh.x += __shfl_xor(rh.x, m, 64);
            rh.y += __shfl_xor(rh.y, m, 64);
            rh.z += __shfl_xor(rh.z, m, 64);
            rh.w += __shfl_xor(rh.w, m, 64);
        }

        // wave-partial M over ALL 64 c: crow-group g covers c = g*16 + j
#pragma unroll
        for (int j4 = 0; j4 < 4; ++j4) {
            const float4 u2v = *reinterpret_cast<const float4*>(
                &U2s[vi][crow * 16 + 4 * j4]);
            mr[4 * j4 + 0].x = fmaf(u2v.x, rh.x, mr[4 * j4 + 0].x);
            mr[4 * j4 + 0].y = fmaf(u2v.x, rh.y, mr[4 * j4 + 0].y);
            mr[4 * j4 + 0].z = fmaf(u2v.x, rh.z, mr[4 * j4 + 0].z);
            mr[4 * j4 + 0].w = fmaf(u2v.x, rh.w, mr[4 * j4 + 0].w);
            mr[4 * j4 + 1].x = fmaf(u2v.y, rh.x, mr[4 * j4 + 1].x);
            mr[4 * j4 + 1].y = fmaf(u2v.y, rh.y, mr[4 * j4 + 1].y);
            mr[4 * j4 + 1].z = fmaf(u2v.y, rh.z, mr[4 * j4 + 1].z);
            mr[4 * j4 + 1].w = fmaf(u2v.y, rh.w, mr[4 * j4 + 1].w);
            mr[4 * j4 + 2].x = fmaf(u2v.z, rh.x, mr[4 * j4 + 2].x);
            mr[4 * j4 + 2].y = fmaf(u2v.z, rh.y, mr[4 * j4 + 2].y);
            mr[4 * j4 + 2].z = fmaf(u2v.z, rh.z, mr[4 * j4 + 2].z);
            mr[4 * j4 + 2].w = fmaf(u2v.z, rh.w, mr[4 * j4 + 2].w);
            mr[4 * j4 + 3].x = fmaf(u2v.w, rh.x, mr[4 * j4 + 3].x);
            mr[4 * j4 + 3].y = fmaf(u2v.w, rh.y, mr[4 * j4 + 3].y);
            mr[4 * j4 + 3].z = fmaf(u2v.w, rh.z, mr[4 * j4 + 3].z);
            mr[4 * j4 + 3].w = fmaf(u2v.w, rh.w, mr[4 * j4 + 3].w);
        }
    }

    float* pb = part + (size_t)(b * CHUNKS + chunk) * 2 * NC * NT;

    // t1: each (c,u) owned by exactly one lane -> direct coalesced stores
#pragma unroll
    for (int k = 0; k < 4; ++k)
        *reinterpret_cast<float4*>(&pb[(cw + 4 * k) * NT + u0]) = t1r[k];

    // M: sum the 4 wave-partials in LDS (sequential waves, 4 barriers)
    for (int i = 0; i < 4; ++i) {
        if (w == i) {
#pragma unroll
            for (int j = 0; j < 16; ++j) {
                float* d = &Msum[(crow * 16 + j) * NT + u0];
                if (i == 0) {
                    *reinterpret_cast<float4*>(d) = mr[j];
                } else {
                    d[0] += mr[j].x; d[1] += mr[j].y;
                    d[2] += mr[j].z; d[3] += mr[j].w;
                }
            }
        }
        __syncthreads();
    }

    float* pbM = pb + NC * NT;
    for (int i = tid * 4; i < NC * NT; i += 1024)
        *reinterpret_cast<float4*>(&pbM[i]) =
            *reinterpret_cast<const float4*>(&Msum[i]);
}

// ---------------------------------------------------------------------------
// Kernel 2a: reduce the 32 chunk-partials per b (32 MB -> 1 MB).
// 4-accumulator tree to keep loads deep and error low.
// ---------------------------------------------------------------------------
__global__ __launch_bounds__(256) void k2a_reduce(
    const float4* __restrict__ part4,   // (B, CHUNKS, 2048) in float4 units
    float4* __restrict__ fin4)          // (B, 2048)
{
    const int j = blockIdx.x;           // 0..255
    const int b = j >> 3;
    const int local = (j & 7) * 256 + threadIdx.x;  // 0..2047

    const float4* p = part4 + (size_t)b * CHUNKS * 2048 + local;
    float4 a0 = make_float4(0.f, 0.f, 0.f, 0.f);
    float4 a1 = a0, a2 = a0, a3 = a0;
#pragma unroll
    for (int ch = 0; ch < CHUNKS; ch += 4) {
        const float4 v0 = p[(size_t)(ch + 0) * 2048];
        const float4 v1 = p[(size_t)(ch + 1) * 2048];
        const float4 v2 = p[(size_t)(ch + 2) * 2048];
        const float4 v3 = p[(size_t)(ch + 3) * 2048];
        a0.x += v0.x; a0.y += v0.y; a0.z += v0.z; a0.w += v0.w;
        a1.x += v1.x; a1.y += v1.y; a1.z += v1.z; a1.w += v1.w;
        a2.x += v2.x; a2.y += v2.y; a2.z += v2.z; a2.w += v2.w;
        a3.x += v3.x; a3.y += v3.y; a3.z += v3.z; a3.w += v3.w;
    }
    float4 acc;
    acc.x = (a0.x + a1.x) + (a2.x + a3.x);
    acc.y = (a0.y + a1.y) + (a2.y + a3.y);
    acc.z = (a0.z + a1.z) + (a2.z + a3.z);
    acc.w = (a0.w + a1.w) + (a2.w + a3.w);
    fin4[(size_t)b * 2048 + local] = acc;
}

// ---------------------------------------------------------------------------
// Kernel 2b: per-b epilogue. product = t1^T(c,t) · M(c,u); sigmoid(+b_e);
// E = V_e @ sig; softmax over t (axis=1) per column u.
// ---------------------------------------------------------------------------
__global__ __launch_bounds__(256) void k2b_epilogue(
    const float* __restrict__ fin,    // (B, 2, C, T)
    const float* __restrict__ b_e,    // (1, T, T)
    const float* __restrict__ V_e,    // (B, T, T)
    float* __restrict__ out)          // (B, T, T)
{
    const int b = blockIdx.x;
    const int tid = threadIdx.x;

    __shared__ float t1[NC * NT];
    __shared__ float Mb[NC * NT];
    __shared__ float P[NT * NT];
    __shared__ float Eb[NT * NT];

    const float* t1g = fin + (size_t)b * 2 * NC * NT;
    const float* mgb = t1g + NC * NT;
    for (int i = tid * 4; i < NC * NT; i += 1024) {
        *reinterpret_cast<float4*>(&t1[i]) = *reinterpret_cast<const float4*>(&t1g[i]);
        *reinterpret_cast<float4*>(&Mb[i]) = *reinterpret_cast<const float4*>(&mgb[i]);
    }
    __syncthreads();

    const int u  = tid & 63;
    const int tg = tid >> 6;   // wave id, 0..3

    for (int i = 0; i < 16; ++i) {
        const int t = tg * 16 + i;
        float acc = 0.f;
#pragma unroll 8
        for (int c = 0; c < NC; ++c)
            acc = fmaf(t1[c * NT + t], Mb[c * NT + u], acc);
        const float z = acc + b_e[t * NT + u];
        P[t * NT + u] = 1.0f / (1.0f + expf(-z));
    }
    __syncthreads();

    const float* veb = V_e + (size_t)b * NT * NT;
    for (int i = 0; i < 16; ++i) {
        const int t = tg * 16 + i;
        float acc = 0.f;
#pragma unroll 8
        for (int s = 0; s < NT; ++s)
            acc = fmaf(veb[t * NT + s], P[s * NT + u], acc);
        Eb[t * NT + u] = acc;
    }
    __syncthreads();

    if (tid < NT) {
        const int uu = tid;
        float m = -INFINITY;
        for (int t = 0; t < NT; ++t) m = fmaxf(m, Eb[t * NT + uu]);
        float ssum = 0.f;
        for (int t = 0; t < NT; ++t) {
            const float e = expf(Eb[t * NT + uu] - m);
            Eb[t * NT + uu] = e;
            ssum += e;
        }
        const float inv = 1.0f / ssum;
        for (int t = 0; t < NT; ++t)
            out[(size_t)b * NT * NT + t * NT + uu] = Eb[t * NT + uu] * inv;
    }
}

extern "C" void kernel_launch(void* const* d_in, const int* in_sizes, int n_in,
                              void* d_out, int out_size, void* d_ws, size_t ws_size,
                              hipStream_t stream) {
    const float* x   = (const float*)d_in[0];
    const float* U1  = (const float*)d_in[1];
    const float* U2  = (const float*)d_in[2];
    const float* U3  = (const float*)d_in[3];
    const float* b_e = (const float*)d_in[4];
    const float* V_e = (const float*)d_in[5];
    float* out = (float*)d_out;

    float* part = (float*)d_ws;                                   // 32 MB
    float* fin  = part + (size_t)NB * CHUNKS * 2 * NC * NT;       // 1 MB

    // every byte of part/fin is fully written each call -> no zeroing needed
    k1_pass_x<<<NB * CHUNKS, 256, 0, stream>>>(x, U1, U2, U3, part);
    k2a_reduce<<<256, 256, 0, stream>>>((const float4*)part, (float4*)fin);
    k2b_epilogue<<<NB, 256, 0, stream>>>(fin, b_e, V_e, out);
}

// Round 6
// 245.224 us; speedup vs baseline: 1.6330x; 1.0490x over previous
//
#include <hip/hip_runtime.h>
#include <math.h>

#define NB 32
#define NV 2048
#define NC 64
#define NT 64
#define VC 128             // v-values per block in kernel 1
#define CHUNKS (NV / VC)   // 16 chunks per b
#define U2P 68             // padded LDS stride

// ---------------------------------------------------------------------------
// Kernel 1: one pass over x (1 GiB). Coalesced 1KB wave-loads, no per-v
// barriers, explicit 1-deep software prefetch (next v's loads issue BEFORE
// current v's compute so HBM latency hides under the FMA/shfl tail).
// Wave w owns c-quarter [16w,16w+16), all 64 u. Lane l: u0=(l&15)*4,
// crow=l>>4, rows c_k = 16w + crow + 4k.
//   t1r[k] += U1[v] * xa[k]
//   rh = sum_k U3[c_k]*xa[k]; shfl_xor(16,32) -> rhs over wave's 16 c
//   mr[j] += U2[crow*16+j, v] * rh   (wave-partial M over all 64 c, linear)
// Block end: t1 direct store; M = 4 wave-partials summed via LDS.
// 512 blocks = 2/CU resident (LDS 51KB/block) -> zero tail.
// ---------------------------------------------------------------------------
__global__ __launch_bounds__(256) void k1_pass_x(
    const float* __restrict__ x,
    const float* __restrict__ U1,
    const float* __restrict__ U2,   // (C, V)
    const float* __restrict__ U3,   // (C)
    float* __restrict__ part)       // (B, CHUNKS, 2, C, T)
{
    const int tid = threadIdx.x;
    const int blk = blockIdx.x;
    const int b     = blk / CHUNKS;
    const int chunk = blk % CHUNKS;
    const int v0    = chunk * VC;

    const int w    = tid >> 6;        // wave 0..3
    const int l    = tid & 63;        // lane
    const int u0   = (l & 15) * 4;    // float4-aligned u offset
    const int crow = l >> 4;          // 0..3
    const int cw   = w * 16 + crow;   // lane base row; c_k = cw + 4k

    __shared__ float U2s[VC][U2P];    // 34.8 KB
    __shared__ float Msum[NC * NT];   // 16 KB

    for (int i = tid; i < VC * NC; i += 256) {
        const int c  = i >> 7;        // 0..63
        const int vi = i & 127;       // 0..127
        U2s[vi][c] = U2[c * NV + v0 + vi];
    }

    float u3r[4];
#pragma unroll
    for (int k = 0; k < 4; ++k) u3r[k] = U3[cw + 4 * k];

    float4 t1r[4], mr[16];
#pragma unroll
    for (int k = 0; k < 4; ++k) t1r[k] = make_float4(0.f, 0.f, 0.f, 0.f);
#pragma unroll
    for (int j = 0; j < 16; ++j) mr[j] = make_float4(0.f, 0.f, 0.f, 0.f);

    __syncthreads();   // U2s ready

    const float* xb = x + (size_t)(b * NV + v0) * (NC * NT) + cw * NT + u0;

    // prefetch v=0
    float4 xc[4];
#pragma unroll
    for (int k = 0; k < 4; ++k)
        xc[k] = *reinterpret_cast<const float4*>(xb + 4 * k * NT);

#pragma unroll 2
    for (int vi = 0; vi < VC; ++vi) {
        // issue next iteration's loads FIRST (independent of current compute)
        const int vn = (vi + 1 < VC) ? vi + 1 : vi;
        const float* xv = xb + (size_t)vn * (NC * NT);
        float4 xn[4];
#pragma unroll
        for (int k = 0; k < 4; ++k)
            xn[k] = *reinterpret_cast<const float4*>(xv + 4 * k * NT);

        const float u1v = U1[v0 + vi];

        float4 rh = make_float4(0.f, 0.f, 0.f, 0.f);
#pragma unroll
        for (int k = 0; k < 4; ++k) {
            t1r[k].x = fmaf(u1v, xc[k].x, t1r[k].x);
            t1r[k].y = fmaf(u1v, xc[k].y, t1r[k].y);
            t1r[k].z = fmaf(u1v, xc[k].z, t1r[k].z);
            t1r[k].w = fmaf(u1v, xc[k].w, t1r[k].w);
            rh.x = fmaf(u3r[k], xc[k].x, rh.x);
            rh.y = fmaf(u3r[k], xc[k].y, rh.y);
            rh.z = fmaf(u3r[k], xc[k].z, rh.z);
            rh.w = fmaf(u3r[k], xc[k].w, rh.w);
        }

        // complete rhs over this wave's 16 c (sum 4 crow groups)
#pragma unroll
        for (int m = 16; m <= 32; m <<= 1) {
            rh.x += __shfl_xor(rh.x, m, 64);
            rh.y += __shfl_xor(rh.y, m, 64);
            rh.z += __shfl_xor(rh.z, m, 64);
            rh.w += __shfl_xor(rh.w, m, 64);
        }

        // wave-partial M over ALL 64 c
#pragma unroll
        for (int j4 = 0; j4 < 4; ++j4) {
            const float4 u2v = *reinterpret_cast<const float4*>(
                &U2s[vi][crow * 16 + 4 * j4]);
            mr[4 * j4 + 0].x = fmaf(u2v.x, rh.x, mr[4 * j4 + 0].x);
            mr[4 * j4 + 0].y = fmaf(u2v.x, rh.y, mr[4 * j4 + 0].y);
            mr[4 * j4 + 0].z = fmaf(u2v.x, rh.z, mr[4 * j4 + 0].z);
            mr[4 * j4 + 0].w = fmaf(u2v.x, rh.w, mr[4 * j4 + 0].w);
            mr[4 * j4 + 1].x = fmaf(u2v.y, rh.x, mr[4 * j4 + 1].x);
            mr[4 * j4 + 1].y = fmaf(u2v.y, rh.y, mr[4 * j4 + 1].y);
            mr[4 * j4 + 1].z = fmaf(u2v.y, rh.z, mr[4 * j4 + 1].z);
            mr[4 * j4 + 1].w = fmaf(u2v.y, rh.w, mr[4 * j4 + 1].w);
            mr[4 * j4 + 2].x = fmaf(u2v.z, rh.x, mr[4 * j4 + 2].x);
            mr[4 * j4 + 2].y = fmaf(u2v.z, rh.y, mr[4 * j4 + 2].y);
            mr[4 * j4 + 2].z = fmaf(u2v.z, rh.z, mr[4 * j4 + 2].z);
            mr[4 * j4 + 2].w = fmaf(u2v.z, rh.w, mr[4 * j4 + 2].w);
            mr[4 * j4 + 3].x = fmaf(u2v.w, rh.x, mr[4 * j4 + 3].x);
            mr[4 * j4 + 3].y = fmaf(u2v.w, rh.y, mr[4 * j4 + 3].y);
            mr[4 * j4 + 3].z = fmaf(u2v.w, rh.z, mr[4 * j4 + 3].z);
            mr[4 * j4 + 3].w = fmaf(u2v.w, rh.w, mr[4 * j4 + 3].w);
        }

#pragma unroll
        for (int k = 0; k < 4; ++k) xc[k] = xn[k];
    }

    float* pb = part + (size_t)(b * CHUNKS + chunk) * 2 * NC * NT;

    // t1: each (c,u) owned by exactly one lane -> direct coalesced stores
#pragma unroll
    for (int k = 0; k < 4; ++k)
        *reinterpret_cast<float4*>(&pb[(cw + 4 * k) * NT + u0]) = t1r[k];

    // M: sum the 4 wave-partials in LDS (sequential waves, 4 barriers)
    for (int i = 0; i < 4; ++i) {
        if (w == i) {
#pragma unroll
            for (int j = 0; j < 16; ++j) {
                float* d = &Msum[(crow * 16 + j) * NT + u0];
                if (i == 0) {
                    *reinterpret_cast<float4*>(d) = mr[j];
                } else {
                    d[0] += mr[j].x; d[1] += mr[j].y;
                    d[2] += mr[j].z; d[3] += mr[j].w;
                }
            }
        }
        __syncthreads();
    }

    float* pbM = pb + NC * NT;
    for (int i = tid * 4; i < NC * NT; i += 1024)
        *reinterpret_cast<float4*>(&pbM[i]) =
            *reinterpret_cast<const float4*>(&Msum[i]);
}

// ---------------------------------------------------------------------------
// Kernel 2a: reduce the 16 chunk-partials per b (17 MB -> 1 MB).
// ---------------------------------------------------------------------------
__global__ __launch_bounds__(256) void k2a_reduce(
    const float4* __restrict__ part4,   // (B, CHUNKS, 2048) in float4 units
    float4* __restrict__ fin4)          // (B, 2048)
{
    const int j = blockIdx.x;           // 0..255
    const int b = j >> 3;
    const int local = (j & 7) * 256 + threadIdx.x;  // 0..2047

    const float4* p = part4 + (size_t)b * CHUNKS * 2048 + local;
    float4 a0 = make_float4(0.f, 0.f, 0.f, 0.f);
    float4 a1 = a0, a2 = a0, a3 = a0;
#pragma unroll
    for (int ch = 0; ch < CHUNKS; ch += 4) {
        const float4 v0 = p[(size_t)(ch + 0) * 2048];
        const float4 v1 = p[(size_t)(ch + 1) * 2048];
        const float4 v2 = p[(size_t)(ch + 2) * 2048];
        const float4 v3 = p[(size_t)(ch + 3) * 2048];
        a0.x += v0.x; a0.y += v0.y; a0.z += v0.z; a0.w += v0.w;
        a1.x += v1.x; a1.y += v1.y; a1.z += v1.z; a1.w += v1.w;
        a2.x += v2.x; a2.y += v2.y; a2.z += v2.z; a2.w += v2.w;
        a3.x += v3.x; a3.y += v3.y; a3.z += v3.z; a3.w += v3.w;
    }
    float4 acc;
    acc.x = (a0.x + a1.x) + (a2.x + a3.x);
    acc.y = (a0.y + a1.y) + (a2.y + a3.y);
    acc.z = (a0.z + a1.z) + (a2.z + a3.z);
    acc.w = (a0.w + a1.w) + (a2.w + a3.w);
    fin4[(size_t)b * 2048 + local] = acc;
}

// ---------------------------------------------------------------------------
// Kernel 2b: per-b epilogue. product = t1^T(c,t) · M(c,u); sigmoid(+b_e);
// E = V_e @ sig; softmax over t (axis=1) per column u.
// ---------------------------------------------------------------------------
__global__ __launch_bounds__(256) void k2b_epilogue(
    const float* __restrict__ fin,    // (B, 2, C, T)
    const float* __restrict__ b_e,    // (1, T, T)
    const float* __restrict__ V_e,    // (B, T, T)
    float* __restrict__ out)          // (B, T, T)
{
    const int b = blockIdx.x;
    const int tid = threadIdx.x;

    __shared__ float t1[NC * NT];
    __shared__ float Mb[NC * NT];
    __shared__ float P[NT * NT];
    __shared__ float Eb[NT * NT];

    const float* t1g = fin + (size_t)b * 2 * NC * NT;
    const float* mgb = t1g + NC * NT;
    for (int i = tid * 4; i < NC * NT; i += 1024) {
        *reinterpret_cast<float4*>(&t1[i]) = *reinterpret_cast<const float4*>(&t1g[i]);
        *reinterpret_cast<float4*>(&Mb[i]) = *reinterpret_cast<const float4*>(&mgb[i]);
    }
    __syncthreads();

    const int u  = tid & 63;
    const int tg = tid >> 6;   // wave id, 0..3

    for (int i = 0; i < 16; ++i) {
        const int t = tg * 16 + i;
        float acc = 0.f;
#pragma unroll 8
        for (int c = 0; c < NC; ++c)
            acc = fmaf(t1[c * NT + t], Mb[c * NT + u], acc);
        const float z = acc + b_e[t * NT + u];
        P[t * NT + u] = 1.0f / (1.0f + expf(-z));
    }
    __syncthreads();

    const float* veb = V_e + (size_t)b * NT * NT;
    for (int i = 0; i < 16; ++i) {
        const int t = tg * 16 + i;
        float acc = 0.f;
#pragma unroll 8
        for (int s = 0; s < NT; ++s)
            acc = fmaf(veb[t * NT + s], P[s * NT + u], acc);
        Eb[t * NT + u] = acc;
    }
    __syncthreads();

    if (tid < NT) {
        const int uu = tid;
        float m = -INFINITY;
        for (int t = 0; t < NT; ++t) m = fmaxf(m, Eb[t * NT + uu]);
        float ssum = 0.f;
        for (int t = 0; t < NT; ++t) {
            const float e = expf(Eb[t * NT + uu] - m);
            Eb[t * NT + uu] = e;
            ssum += e;
        }
        const float inv = 1.0f / ssum;
        for (int t = 0; t < NT; ++t)
            out[(size_t)b * NT * NT + t * NT + uu] = Eb[t * NT + uu] * inv;
    }
}

extern "C" void kernel_launch(void* const* d_in, const int* in_sizes, int n_in,
                              void* d_out, int out_size, void* d_ws, size_t ws_size,
                              hipStream_t stream) {
    const float* x   = (const float*)d_in[0];
    const float* U1  = (const float*)d_in[1];
    const float* U2  = (const float*)d_in[2];
    const float* U3  = (const float*)d_in[3];
    const float* b_e = (const float*)d_in[4];
    const float* V_e = (const float*)d_in[5];
    float* out = (float*)d_out;

    float* part = (float*)d_ws;                                   // 16.8 MB
    float* fin  = part + (size_t)NB * CHUNKS * 2 * NC * NT;       // 1 MB

    // every byte of part/fin is fully written each call -> no zeroing needed
    k1_pass_x<<<NB * CHUNKS, 256, 0, stream>>>(x, U1, U2, U3, part);
    k2a_reduce<<<256, 256, 0, stream>>>((const float4*)part, (float4*)fin);
    k2b_epilogue<<<NB, 256, 0, stream>>>(fin, b_e, V_e, out);
}